// Round 14
// baseline (125.039 us; speedup 1.0000x reference)
//
#include <hip/hip_runtime.h>
#include <math.h>

#define N_EMBD    4096
#define N_EXPERTS 64
#define N_TOKENS  16384
#define TAU       1e-3f
#define KS        8                   // K-split across waves
#define KSTEPS    16                  // K-steps of 32 per wave (512 f32)

typedef __attribute__((ext_vector_type(8))) short bf16x8;
typedef __attribute__((ext_vector_type(4))) float f32x4;
typedef __attribute__((ext_vector_type(4))) unsigned u32x4;

#define MFMA16 __builtin_amdgcn_mfma_f32_16x16x32_bf16

struct hl_pair { unsigned h, l; };

// ---------------------------------------------------------------------------
// f32 -> (bf16 hi, bf16 lo) RNE split, pair-packed into one u32 each.
// ---------------------------------------------------------------------------
__device__ __forceinline__ hl_pair split_pair(float f0, float f1) {
    unsigned u0 = __builtin_bit_cast(unsigned, f0);
    unsigned u1 = __builtin_bit_cast(unsigned, f1);
    unsigned r0 = u0 + 0x7FFFu + ((u0 >> 16) & 1u);
    unsigned r1 = u1 + 0x7FFFu + ((u1 >> 16) & 1u);
    hl_pair p;
    p.h = (r0 >> 16) | (r1 & 0xFFFF0000u);
    float h0 = __builtin_bit_cast(float, r0 & 0xFFFF0000u);
    float h1 = __builtin_bit_cast(float, r1 & 0xFFFF0000u);
    float l0 = f0 - h0;
    float l1 = f1 - h1;
    unsigned v0 = __builtin_bit_cast(unsigned, l0);
    unsigned v1 = __builtin_bit_cast(unsigned, l1);
    unsigned s0 = v0 + 0x7FFFu + ((v0 >> 16) & 1u);
    unsigned s1 = v1 + 0x7FFFu + ((v1 >> 16) & 1u);
    p.l = (s0 >> 16) | (s1 & 0xFFFF0000u);
    return p;
}

// ---------------------------------------------------------------------------
// Kernel 0: pack W into bf16 hi/lo MFMA B-fragments; zero the flag counter.
// Frag F = ks*8 + nt*2 + term. Lane l elem j = W[nt*16+(l&15)][ks*32+(l>>4)*8+j]
// ---------------------------------------------------------------------------
__global__ void w_pack_bf16(const float* __restrict__ W,
                            uint4* __restrict__ Bpack,
                            int* __restrict__ flags) {
    int tid = blockIdx.x * blockDim.x + threadIdx.x;   // 32768
    if (tid == 0) flags[0] = 0;
    int lane = tid & 63;
    int nt   = (tid >> 6) & 3;
    int ks   = tid >> 8;                               // 0..127
    int e = nt * 16 + (lane & 15);
    int k = ks * 32 + ((lane >> 4) << 3);
    const float* src = W + (size_t)e * N_EMBD + k;
    uint4 hp, lp;
    hl_pair p0 = split_pair(src[0], src[1]);
    hl_pair p1 = split_pair(src[2], src[3]);
    hl_pair p2 = split_pair(src[4], src[5]);
    hl_pair p3 = split_pair(src[6], src[7]);
    hp.x = p0.h; lp.x = p0.l;
    hp.y = p1.h; lp.y = p1.l;
    hp.z = p2.h; lp.z = p2.l;
    hp.w = p3.h; lp.w = p3.l;
    size_t F = (size_t)ks * 8 + nt * 2;
    Bpack[F * 64 + lane]       = hp;
    Bpack[(F + 1) * 64 + lane] = lp;
}

// ---------------------------------------------------------------------------
// Split one M-tile's 8 f32 (two f32x4) into hi/lo bf16x8 fragments.
// ---------------------------------------------------------------------------
__device__ __forceinline__ void split_tile(f32x4 A0, f32x4 A1,
                                           bf16x8& ah, bf16x8& al) {
    u32x4 hu, lu;
    hl_pair p;
    p = split_pair(A0.x, A0.y); hu.x = p.h; lu.x = p.l;
    p = split_pair(A0.z, A0.w); hu.y = p.h; lu.y = p.l;
    p = split_pair(A1.x, A1.y); hu.z = p.h; lu.z = p.l;
    p = split_pair(A1.z, A1.w); hu.w = p.h; lu.w = p.l;
    ah = __builtin_bit_cast(bf16x8, hu);
    al = __builtin_bit_cast(bf16x8, lu);
}

// ---------------------------------------------------------------------------
// One K-step, 2 M-tiles: 24 MFMAs; B fragments shared across both M-tiles.
// ---------------------------------------------------------------------------
__device__ __forceinline__ void step2(
        f32x4 A0, f32x4 A1, f32x4 A2, f32x4 A3,
        uint4 B0, uint4 B1, uint4 B2, uint4 B3,
        uint4 B4, uint4 B5, uint4 B6, uint4 B7,
        f32x4& c00, f32x4& c01, f32x4& c02, f32x4& c03,
        f32x4& c10, f32x4& c11, f32x4& c12, f32x4& c13) {
    bf16x8 ah0, al0, ah1, al1;
    split_tile(A0, A1, ah0, al0);
    split_tile(A2, A3, ah1, al1);
    bf16x8 bh, bl;
    bh = __builtin_bit_cast(bf16x8, B0); bl = __builtin_bit_cast(bf16x8, B1);
    c00 = MFMA16(ah0, bh, c00, 0, 0, 0);
    c00 = MFMA16(ah0, bl, c00, 0, 0, 0);
    c00 = MFMA16(al0, bh, c00, 0, 0, 0);
    c10 = MFMA16(ah1, bh, c10, 0, 0, 0);
    c10 = MFMA16(ah1, bl, c10, 0, 0, 0);
    c10 = MFMA16(al1, bh, c10, 0, 0, 0);
    bh = __builtin_bit_cast(bf16x8, B2); bl = __builtin_bit_cast(bf16x8, B3);
    c01 = MFMA16(ah0, bh, c01, 0, 0, 0);
    c01 = MFMA16(ah0, bl, c01, 0, 0, 0);
    c01 = MFMA16(al0, bh, c01, 0, 0, 0);
    c11 = MFMA16(ah1, bh, c11, 0, 0, 0);
    c11 = MFMA16(ah1, bl, c11, 0, 0, 0);
    c11 = MFMA16(al1, bh, c11, 0, 0, 0);
    bh = __builtin_bit_cast(bf16x8, B4); bl = __builtin_bit_cast(bf16x8, B5);
    c02 = MFMA16(ah0, bh, c02, 0, 0, 0);
    c02 = MFMA16(ah0, bl, c02, 0, 0, 0);
    c02 = MFMA16(al0, bh, c02, 0, 0, 0);
    c12 = MFMA16(ah1, bh, c12, 0, 0, 0);
    c12 = MFMA16(ah1, bl, c12, 0, 0, 0);
    c12 = MFMA16(al1, bh, c12, 0, 0, 0);
    bh = __builtin_bit_cast(bf16x8, B6); bl = __builtin_bit_cast(bf16x8, B7);
    c03 = MFMA16(ah0, bh, c03, 0, 0, 0);
    c03 = MFMA16(ah0, bl, c03, 0, 0, 0);
    c03 = MFMA16(al0, bh, c03, 0, 0, 0);
    c13 = MFMA16(ah1, bh, c13, 0, 0, 0);
    c13 = MFMA16(ah1, bl, c13, 0, 0, 0);
    c13 = MFMA16(al1, bh, c13, 0, 0, 0);
}

// ---------------------------------------------------------------------------
// Kernel 1: router GEMM — pure fragment-gather, NO LDS, NO barriers.
// Wave = 32 tokens x 64 experts x 512-K slice (16 K-steps). 4096 independent
// waves = 16 waves/CU = 4/SIMD: TLP hides gather latency (the r6 structure's
// only defect was 2/SIMD occupancy; r12 counters proved latency-bound).
// LDS round-trip eliminated -> no LDS pipe cost, no barrier serialization.
// partial layout: [KS][N_TOKENS][64] f32.
// ---------------------------------------------------------------------------
__global__ __launch_bounds__(256, 4) void router_gemm(
        const float* __restrict__ x,
        const uint4* __restrict__ Bpack,
        float* __restrict__ partial) {
    const int tid  = threadIdx.x;
    const int lane = tid & 63;
    const int wid  = blockIdx.x * 4 + (tid >> 6);
    const int kq   = wid & 7;                    // K-eighth
    const int tg   = wid >> 3;                   // token group 0..511
    const int tok0 = tg * 32;
    const int l15 = lane & 15, l16 = lane >> 4;

    // A fragment gather: lane l -> row l&15 (M-tile 0) / +16 (M-tile 1),
    // k-offset (l>>4)*8 within each K-step of 32.
    const f32x4* pa0 = (const f32x4*)x + (size_t)(tok0 + l15) * (N_EMBD / 4)
                     + kq * (N_EMBD / 4 / KS) + l16 * 2;
    const f32x4* pa1 = pa0 + (size_t)16 * (N_EMBD / 4);
    // B fragments for K-steps [kq*16, kq*16+16)
    const uint4* pb = Bpack + ((size_t)kq * KSTEPS * 8) * 64 + lane;

    f32x4 c00 = {0.f,0.f,0.f,0.f}, c01 = {0.f,0.f,0.f,0.f};
    f32x4 c02 = {0.f,0.f,0.f,0.f}, c03 = {0.f,0.f,0.f,0.f};
    f32x4 c10 = {0.f,0.f,0.f,0.f}, c11 = {0.f,0.f,0.f,0.f};
    f32x4 c12 = {0.f,0.f,0.f,0.f}, c13 = {0.f,0.f,0.f,0.f};

    f32x4 aa0, aa1, aa2, aa3, ab0, ab1, ab2, ab3;

#define LOADA(P, s) { P##0 = pa0[(s) * 8]; P##1 = pa0[(s) * 8 + 1];            \
                      P##2 = pa1[(s) * 8]; P##3 = pa1[(s) * 8 + 1]; }

    LOADA(aa, 0);
    for (int s = 0; s < KSTEPS; s += 2) {
        LOADA(ab, s + 1);
        {
            const uint4* q = pb + (size_t)s * 512;
            uint4 B0 = q[0],   B1 = q[64],  B2 = q[128], B3 = q[192];
            uint4 B4 = q[256], B5 = q[320], B6 = q[384], B7 = q[448];
            step2(aa0, aa1, aa2, aa3, B0, B1, B2, B3, B4, B5, B6, B7,
                  c00, c01, c02, c03, c10, c11, c12, c13);
        }
        if (s + 2 < KSTEPS) LOADA(aa, s + 2);
        {
            const uint4* q = pb + (size_t)(s + 1) * 512;
            uint4 B0 = q[0],   B1 = q[64],  B2 = q[128], B3 = q[192];
            uint4 B4 = q[256], B5 = q[320], B6 = q[384], B7 = q[448];
            step2(ab0, ab1, ab2, ab3, B0, B1, B2, B3, B4, B5, B6, B7,
                  c00, c01, c02, c03, c10, c11, c12, c13);
        }
    }
#undef LOADA

    // C layout: row(token in M-tile) = (lane>>4)*4 + reg, col = lane&15;
    // expert = nt*16 + l15.
    float* po = partial + ((size_t)kq * N_TOKENS + tok0) * 64 + l15;
#pragma unroll
    for (int j = 0; j < 4; ++j) {
        size_t r0 = (size_t)(l16 * 4 + j) * 64;
        size_t r1 = (size_t)(16 + l16 * 4 + j) * 64;
        po[r0 +  0] = c00[j];
        po[r0 + 16] = c01[j];
        po[r0 + 32] = c02[j];
        po[r0 + 48] = c03[j];
        po[r1 +  0] = c10[j];
        po[r1 + 16] = c11[j];
        po[r1 + 32] = c12[j];
        po[r1 + 48] = c13[j];
    }
}

// ---------------------------------------------------------------------------
// Kernel 2: finalize. Wave per token; sum 8 K-slice partials; top-3
// butterflies; softmax of top-2; near-tie flagging for refine.
// ---------------------------------------------------------------------------
__global__ void finalize(const float* __restrict__ partial,
                         float* __restrict__ out,
                         int* __restrict__ flags) {
    const int lane = threadIdx.x & 63;
    const int tok  = blockIdx.x * 4 + (threadIdx.x >> 6);

    float v = 0.0f;
#pragma unroll
    for (int q = 0; q < KS; ++q)
        v += partial[((size_t)q * N_TOKENS + tok) * 64 + lane];

    float m1 = v; int i1 = lane;
#pragma unroll
    for (int off = 32; off; off >>= 1) {
        float ov = __shfl_xor(m1, off); int oi = __shfl_xor(i1, off);
        if (ov > m1 || (ov == m1 && oi < i1)) { m1 = ov; i1 = oi; }
    }
    float m2 = (lane == i1) ? -INFINITY : v; int i2 = lane;
#pragma unroll
    for (int off = 32; off; off >>= 1) {
        float ov = __shfl_xor(m2, off); int oi = __shfl_xor(i2, off);
        if (ov > m2 || (ov == m2 && oi < i2)) { m2 = ov; i2 = oi; }
    }
    float m3 = (lane == i1 || lane == i2) ? -INFINITY : v;
#pragma unroll
    for (int off = 32; off; off >>= 1)
        m3 = fmaxf(m3, __shfl_xor(m3, off));

    if (lane == 0) {
        float e2  = __expf(m2 - m1);
        float inv = 1.0f / (1.0f + e2);
        float2 idx = make_float2((float)i1, (float)i2);
        float2 gts = make_float2(inv, e2 * inv);
        *(float2*)(out + 2 * tok) = idx;
        *(float2*)(out + 2 * N_TOKENS + 2 * tok) = gts;
        if ((m1 - m2 < TAU) || (m2 - m3 < TAU)) {
            int p = atomicAdd(flags, 1);
            if (p < N_TOKENS) flags[1 + p] = tok;
        }
    }
}

// ---------------------------------------------------------------------------
// Kernel 3: exact f64 refinement of flagged near-tie tokens. Block per token
// (grid-strided). Wave wv handles experts wv*16..+16, lanes split K.
// ---------------------------------------------------------------------------
__global__ __launch_bounds__(256) void refine(const float* __restrict__ x,
                                              const float* __restrict__ W,
                                              const int* __restrict__ flags,
                                              float* __restrict__ out) {
    __shared__ double redd[64];
    const int lane = threadIdx.x & 63;
    const int wv   = threadIdx.x >> 6;
    int cnt = flags[0];
    if (cnt > N_TOKENS) cnt = N_TOKENS;

    for (int i = blockIdx.x; i < cnt; i += gridDim.x) {
        const int tok = flags[1 + i];
        const float4* xr4 = (const float4*)(x + (size_t)tok * N_EMBD);
#pragma unroll
        for (int ee = 0; ee < 16; ++ee) {
            const int e = wv * 16 + ee;
            const float4* wr = (const float4*)(W + (size_t)e * N_EMBD);
            double acc = 0.0;
#pragma unroll 4
            for (int c = 0; c < 16; ++c) {
                float4 xv = xr4[c * 64 + lane];
                float4 wq = wr[c * 64 + lane];
                acc += (double)xv.x * wq.x + (double)xv.y * wq.y
                     + (double)xv.z * wq.z + (double)xv.w * wq.w;
            }
#pragma unroll
            for (int off = 32; off; off >>= 1)
                acc += __shfl_xor(acc, off);
            if (lane == 0) redd[e] = acc;
        }
        __syncthreads();
        if (wv == 0) {
            double v = redd[lane];
            double m1 = v; int i1 = lane;
#pragma unroll
            for (int off = 32; off; off >>= 1) {
                double ov = __shfl_xor(m1, off); int oi = __shfl_xor(i1, off);
                if (ov > m1 || (ov == m1 && oi < i1)) { m1 = ov; i1 = oi; }
            }
            double m2 = (lane == i1) ? -INFINITY : v; int i2 = lane;
#pragma unroll
            for (int off = 32; off; off >>= 1) {
                double ov = __shfl_xor(m2, off); int oi = __shfl_xor(i2, off);
                if (ov > m2 || (ov == m2 && oi < i2)) { m2 = ov; i2 = oi; }
            }
            if (lane == 0) {
                double e2  = exp(m2 - m1);
                double inv = 1.0 / (1.0 + e2);
                out[2 * tok + 0] = (float)i1;
                out[2 * tok + 1] = (float)i2;
                out[2 * N_TOKENS + 2 * tok + 0] = (float)inv;
                out[2 * N_TOKENS + 2 * tok + 1] = (float)(e2 * inv);
            }
        }
        __syncthreads();
    }
}

// ---------------------------------------------------------------------------
extern "C" void kernel_launch(void* const* d_in, const int* in_sizes, int n_in,
                              void* d_out, int out_size, void* d_ws, size_t ws_size,
                              hipStream_t stream) {
    const float* x = (const float*)d_in[0];
    const float* W = (const float*)d_in[1];
    float* out = (float*)d_out;

    uint4* Bpack   = (uint4*)d_ws;                           // [0, 1MB)
    int*   flags   = (int*)((char*)d_ws + (1u << 20));       // [1MB, +64KB)
    float* partial = (float*)((char*)d_ws + (2u << 20));     // [2MB, 2MB+32MB)

    w_pack_bf16<<<128, 256, 0, stream>>>(W, Bpack, flags);
    router_gemm<<<(N_TOKENS / 32) * KS / 4, 256, 0, stream>>>(x, Bpack, partial);
    finalize   <<<N_TOKENS / 4, 256, 0, stream>>>(partial, out, flags);
    refine     <<<128, 256, 0, stream>>>(x, W, flags, out);
}

// Round 15
// 114.203 us; speedup vs baseline: 1.0949x; 1.0949x over previous
//
#include <hip/hip_runtime.h>
#include <math.h>

#define N_EMBD    4096
#define N_EXPERTS 64
#define N_TOKENS  16384
#define TAU       1e-3f
#define NT_BLK    32                  // tokens per block
#define KS        4                   // K-split across blocks
#define K_BLK     (N_EMBD / KS)       // 1024 f32 per block
#define NT2       16                  // K-tiles (BK=64) per block

typedef __attribute__((ext_vector_type(8))) short bf16x8;
typedef __attribute__((ext_vector_type(4))) float f32x4;

#define MFMA16 __builtin_amdgcn_mfma_f32_16x16x32_bf16
// keep-alive pin: forces the loaded value to be materialized HERE (rule #17),
// preventing the compiler from sinking the load to its use site.
#define PIN2(a, b) asm volatile("" :: "v"(a), "v"(b))

struct hl_pair { unsigned h, l; };

// ---------------------------------------------------------------------------
// f32 -> (bf16 hi, bf16 lo) RNE split, pair-packed into one u32 each.
// ---------------------------------------------------------------------------
__device__ __forceinline__ hl_pair split_pair(float f0, float f1) {
    unsigned u0 = __builtin_bit_cast(unsigned, f0);
    unsigned u1 = __builtin_bit_cast(unsigned, f1);
    unsigned r0 = u0 + 0x7FFFu + ((u0 >> 16) & 1u);
    unsigned r1 = u1 + 0x7FFFu + ((u1 >> 16) & 1u);
    hl_pair p;
    p.h = (r0 >> 16) | (r1 & 0xFFFF0000u);
    float h0 = __builtin_bit_cast(float, r0 & 0xFFFF0000u);
    float h1 = __builtin_bit_cast(float, r1 & 0xFFFF0000u);
    float l0 = f0 - h0;
    float l1 = f1 - h1;
    unsigned v0 = __builtin_bit_cast(unsigned, l0);
    unsigned v1 = __builtin_bit_cast(unsigned, l1);
    unsigned s0 = v0 + 0x7FFFu + ((v0 >> 16) & 1u);
    unsigned s1 = v1 + 0x7FFFu + ((v1 >> 16) & 1u);
    p.l = (s0 >> 16) | (s1 & 0xFFFF0000u);
    return p;
}

// ---------------------------------------------------------------------------
// Kernel 0: pack W into bf16 hi/lo MFMA B-fragments; zero the flag counter.
// Frag F = ks*8 + nt*2 + term. Lane l elem j = W[nt*16+(l&15)][ks*32+(l>>4)*8+j]
// ---------------------------------------------------------------------------
__global__ void w_pack_bf16(const float* __restrict__ W,
                            uint4* __restrict__ Bpack,
                            int* __restrict__ flags) {
    int tid = blockIdx.x * blockDim.x + threadIdx.x;   // 32768
    if (tid == 0) flags[0] = 0;
    int lane = tid & 63;
    int nt   = (tid >> 6) & 3;
    int ks   = tid >> 8;                               // 0..127
    int e = nt * 16 + (lane & 15);
    int k = ks * 32 + ((lane >> 4) << 3);
    const float* src = W + (size_t)e * N_EMBD + k;
    uint4 hp, lp;
    hl_pair p0 = split_pair(src[0], src[1]);
    hl_pair p1 = split_pair(src[2], src[3]);
    hl_pair p2 = split_pair(src[4], src[5]);
    hl_pair p3 = split_pair(src[6], src[7]);
    hp.x = p0.h; lp.x = p0.l;
    hp.y = p1.h; lp.y = p1.l;
    hp.z = p2.h; lp.z = p2.l;
    hp.w = p3.h; lp.w = p3.l;
    size_t F = (size_t)ks * 8 + nt * 2;
    Bpack[F * 64 + lane]       = hp;
    Bpack[(F + 1) * 64 + lane] = lp;
}

// ---------------------------------------------------------------------------
// Split 8 f32 into bf16 hi/lo uint4s and ds_write_b128 to the two planes.
// ---------------------------------------------------------------------------
__device__ __forceinline__ void store_split8(char* buf, int off, f32x4 a, f32x4 b) {
    hl_pair p0 = split_pair(a.x, a.y);
    hl_pair p1 = split_pair(a.z, a.w);
    hl_pair p2 = split_pair(b.x, b.y);
    hl_pair p3 = split_pair(b.z, b.w);
    uint4 h, l;
    h.x = p0.h; h.y = p1.h; h.z = p2.h; h.w = p3.h;
    l.x = p0.l; l.y = p1.l; l.z = p2.l; l.w = p3.l;
    *(uint4*)(buf + off)        = h;
    *(uint4*)(buf + off + 4096) = l;
}

// ---------------------------------------------------------------------------
// Kernel 1: router GEMM, K-split x4, LDS dbuf, PINNED 2-deep A prefetch.
// The r6..r14 plateau diagnosis: reported VGPR 44-52 on kernels declaring
// 80+ regs of prefetch state => compiler was SINKING prefetch loads to use
// sites (full latency exposed per tile, lockstepped by barriers). Fix:
// asm keep-alive pins force loads to materialize 2 tiles ahead;
// launch_bounds(256,4) gives the allocator room (r13's (256,8)=64-VGPR cap
// made register prefetch impossible).
// Block = 32 tokens x 1 K-quarter; wave w = experts [16w,16w+16), 2 M-tiles.
// partial layout: [KS][N_TOKENS][64] f32.
// ---------------------------------------------------------------------------
__global__ __launch_bounds__(256, 4) void router_gemm(
        const float* __restrict__ x,
        const uint4* __restrict__ Bpack,
        float* __restrict__ partial) {
    __shared__ __align__(16) char ldsA[2 * 8192];   // dbuf x {hi 4KB, lo 4KB}

    const int tid  = threadIdx.x;
    const int lane = tid & 63;
    const int w    = tid >> 6;                  // wave = expert quarter
    const int kq   = blockIdx.x & 3;            // K quarter
    const int tok0 = (blockIdx.x >> 2) * NT_BLK;
    const int l15 = lane & 15, l16 = lane >> 4;

    // staging: thread -> row tid>>3 (0..31), 8-f32 chunk c8 = tid&7
    const int row_w = tid >> 3;
    const int c8    = tid & 7;
    const f32x4* g = (const f32x4*)(x + (size_t)(tok0 + row_w) * N_EMBD
                                      + kq * K_BLK + c8 * 8);
    const int wo = row_w * 128 + ((c8 * 16) ^ ((row_w & 7) << 4));

    // fragment read offsets (conflict-free: 8 lanes/bank-quad both sides)
    const int swz_r = (l15 & 7) << 4;
    const int ro0 = l15 * 128 + ((l16 * 16)      ^ swz_r);
    const int ro1 = l15 * 128 + ((64 + l16 * 16) ^ swz_r);

    f32x4 acc0 = {0.f, 0.f, 0.f, 0.f};
    f32x4 acc1 = {0.f, 0.f, 0.f, 0.f};
    f32x4 ra0, ra1, rb0, rb1;

    char* buf0 = ldsA;
    char* buf1 = ldsA + 8192;

    const uint4* bbase = Bpack + ((size_t)(kq * 32) * 8 + w * 2) * 64 + lane;

#define LOADA(P, t) { P##0 = g[(t) * 16]; P##1 = g[(t) * 16 + 1]; }
#define STOREA(buf, P) store_split8(buf, wo, P##0, P##1)
#define COMPUTE(bufR, tt) {                                                   \
    const uint4* bq = bbase + (size_t)(tt) * 1024;                            \
    uint4 bh0q = bq[0];   uint4 bl0q = bq[64];                                \
    uint4 bh1q = bq[512]; uint4 bl1q = bq[576];                               \
    bf16x8 bh0 = __builtin_bit_cast(bf16x8, bh0q);                            \
    bf16x8 bl0 = __builtin_bit_cast(bf16x8, bl0q);                            \
    bf16x8 bh1 = __builtin_bit_cast(bf16x8, bh1q);                            \
    bf16x8 bl1 = __builtin_bit_cast(bf16x8, bl1q);                            \
    bf16x8 a;                                                                 \
    a = *(const bf16x8*)((bufR) + ro0);                                       \
    acc0 = MFMA16(a, bh0, acc0, 0, 0, 0);                                     \
    acc0 = MFMA16(a, bl0, acc0, 0, 0, 0);                                     \
    a = *(const bf16x8*)((bufR) + ro0 + 4096);                                \
    acc0 = MFMA16(a, bh0, acc0, 0, 0, 0);                                     \
    a = *(const bf16x8*)((bufR) + ro0 + 2048);                                \
    acc1 = MFMA16(a, bh0, acc1, 0, 0, 0);                                     \
    acc1 = MFMA16(a, bl0, acc1, 0, 0, 0);                                     \
    a = *(const bf16x8*)((bufR) + ro0 + 2048 + 4096);                         \
    acc1 = MFMA16(a, bh0, acc1, 0, 0, 0);                                     \
    a = *(const bf16x8*)((bufR) + ro1);                                       \
    acc0 = MFMA16(a, bh1, acc0, 0, 0, 0);                                     \
    acc0 = MFMA16(a, bl1, acc0, 0, 0, 0);                                     \
    a = *(const bf16x8*)((bufR) + ro1 + 4096);                                \
    acc0 = MFMA16(a, bh1, acc0, 0, 0, 0);                                     \
    a = *(const bf16x8*)((bufR) + ro1 + 2048);                                \
    acc1 = MFMA16(a, bh1, acc1, 0, 0, 0);                                     \
    acc1 = MFMA16(a, bl1, acc1, 0, 0, 0);                                     \
    a = *(const bf16x8*)((bufR) + ro1 + 2048 + 4096);                         \
    acc1 = MFMA16(a, bh1, acc1, 0, 0, 0);                                     \
}

    // prologue: stage tile 0; pinned prefetch of tiles 1 (rb) and 2 (ra)
    LOADA(rb, 0);
    STOREA(buf0, rb);                          // one-time stall
    LOADA(rb, 1);
    LOADA(ra, 2);
    PIN2(rb0, rb1);
    PIN2(ra0, ra1);
    asm volatile("s_waitcnt lgkmcnt(0)" ::: "memory");
    __builtin_amdgcn_s_barrier();
    __builtin_amdgcn_sched_barrier(0);

    for (int t = 0; t < NT2; t += 2) {
        // ---- tile t (buf0); rb holds tile t+1 (issued 2 tiles ago) ----
        COMPUTE(buf0, t);
        STOREA(buf1, rb);
        if (t + 3 < NT2) { LOADA(rb, t + 3); PIN2(rb0, rb1); }
        asm volatile("s_waitcnt lgkmcnt(0)" ::: "memory");
        __builtin_amdgcn_s_barrier();
        __builtin_amdgcn_sched_barrier(0);

        // ---- tile t+1 (buf1); ra holds tile t+2 ----
        COMPUTE(buf1, t + 1);
        if (t + 2 < NT2) {
            STOREA(buf0, ra);
            if (t + 4 < NT2) { LOADA(ra, t + 4); PIN2(ra0, ra1); }
            asm volatile("s_waitcnt lgkmcnt(0)" ::: "memory");
            __builtin_amdgcn_s_barrier();
            __builtin_amdgcn_sched_barrier(0);
        }
    }
#undef LOADA
#undef STOREA
#undef COMPUTE

    // C layout: row(token in M-tile) = l16*4 + j, col(expert in quarter) = l15
    float* po = partial + ((size_t)kq * N_TOKENS + tok0) * 64 + w * 16 + l15;
#pragma unroll
    for (int j = 0; j < 4; ++j) {
        po[(size_t)(l16 * 4 + j) * 64]      = acc0[j];
        po[(size_t)(16 + l16 * 4 + j) * 64] = acc1[j];
    }
}

// ---------------------------------------------------------------------------
// Kernel 2: finalize. Wave per token; sum 4 K-quarter partials; top-3
// butterflies; softmax of top-2; near-tie flagging for refine.
// ---------------------------------------------------------------------------
__global__ void finalize(const float* __restrict__ partial,
                         float* __restrict__ out,
                         int* __restrict__ flags) {
    const int lane = threadIdx.x & 63;
    const int tok  = blockIdx.x * 4 + (threadIdx.x >> 6);

    float v = partial[(size_t)tok * 64 + lane]
            + partial[((size_t)N_TOKENS + tok) * 64 + lane]
            + partial[((size_t)2 * N_TOKENS + tok) * 64 + lane]
            + partial[((size_t)3 * N_TOKENS + tok) * 64 + lane];

    float m1 = v; int i1 = lane;
#pragma unroll
    for (int off = 32; off; off >>= 1) {
        float ov = __shfl_xor(m1, off); int oi = __shfl_xor(i1, off);
        if (ov > m1 || (ov == m1 && oi < i1)) { m1 = ov; i1 = oi; }
    }
    float m2 = (lane == i1) ? -INFINITY : v; int i2 = lane;
#pragma unroll
    for (int off = 32; off; off >>= 1) {
        float ov = __shfl_xor(m2, off); int oi = __shfl_xor(i2, off);
        if (ov > m2 || (ov == m2 && oi < i2)) { m2 = ov; i2 = oi; }
    }
    float m3 = (lane == i1 || lane == i2) ? -INFINITY : v;
#pragma unroll
    for (int off = 32; off; off >>= 1)
        m3 = fmaxf(m3, __shfl_xor(m3, off));

    if (lane == 0) {
        float e2  = __expf(m2 - m1);
        float inv = 1.0f / (1.0f + e2);
        float2 idx = make_float2((float)i1, (float)i2);
        float2 gts = make_float2(inv, e2 * inv);
        *(float2*)(out + 2 * tok) = idx;
        *(float2*)(out + 2 * N_TOKENS + 2 * tok) = gts;
        if ((m1 - m2 < TAU) || (m2 - m3 < TAU)) {
            int p = atomicAdd(flags, 1);
            if (p < N_TOKENS) flags[1 + p] = tok;
        }
    }
}

// ---------------------------------------------------------------------------
// Kernel 3: exact f64 refinement of flagged near-tie tokens. Block per token
// (grid-strided). Wave wv handles experts wv*16..+16, lanes split K.
// ---------------------------------------------------------------------------
__global__ __launch_bounds__(256) void refine(const float* __restrict__ x,
                                              const float* __restrict__ W,
                                              const int* __restrict__ flags,
                                              float* __restrict__ out) {
    __shared__ double redd[64];
    const int lane = threadIdx.x & 63;
    const int wv   = threadIdx.x >> 6;
    int cnt = flags[0];
    if (cnt > N_TOKENS) cnt = N_TOKENS;

    for (int i = blockIdx.x; i < cnt; i += gridDim.x) {
        const int tok = flags[1 + i];
        const float4* xr4 = (const float4*)(x + (size_t)tok * N_EMBD);
#pragma unroll
        for (int ee = 0; ee < 16; ++ee) {
            const int e = wv * 16 + ee;
            const float4* wr = (const float4*)(W + (size_t)e * N_EMBD);
            double acc = 0.0;
#pragma unroll 4
            for (int c = 0; c < 16; ++c) {
                float4 xv = xr4[c * 64 + lane];
                float4 wq = wr[c * 64 + lane];
                acc += (double)xv.x * wq.x + (double)xv.y * wq.y
                     + (double)xv.z * wq.z + (double)xv.w * wq.w;
            }
#pragma unroll
            for (int off = 32; off; off >>= 1)
                acc += __shfl_xor(acc, off);
            if (lane == 0) redd[e] = acc;
        }
        __syncthreads();
        if (wv == 0) {
            double v = redd[lane];
            double m1 = v; int i1 = lane;
#pragma unroll
            for (int off = 32; off; off >>= 1) {
                double ov = __shfl_xor(m1, off); int oi = __shfl_xor(i1, off);
                if (ov > m1 || (ov == m1 && oi < i1)) { m1 = ov; i1 = oi; }
            }
            double m2 = (lane == i1) ? -INFINITY : v; int i2 = lane;
#pragma unroll
            for (int off = 32; off; off >>= 1) {
                double ov = __shfl_xor(m2, off); int oi = __shfl_xor(i2, off);
                if (ov > m2 || (ov == m2 && oi < i2)) { m2 = ov; i2 = oi; }
            }
            if (lane == 0) {
                double e2  = exp(m2 - m1);
                double inv = 1.0 / (1.0 + e2);
                out[2 * tok + 0] = (float)i1;
                out[2 * tok + 1] = (float)i2;
                out[2 * N_TOKENS + 2 * tok + 0] = (float)inv;
                out[2 * N_TOKENS + 2 * tok + 1] = (float)(e2 * inv);
            }
        }
        __syncthreads();
    }
}

// ---------------------------------------------------------------------------
extern "C" void kernel_launch(void* const* d_in, const int* in_sizes, int n_in,
                              void* d_out, int out_size, void* d_ws, size_t ws_size,
                              hipStream_t stream) {
    const float* x = (const float*)d_in[0];
    const float* W = (const float*)d_in[1];
    float* out = (float*)d_out;

    uint4* Bpack   = (uint4*)d_ws;                           // [0, 1MB)
    int*   flags   = (int*)((char*)d_ws + (1u << 20));       // [1MB, +64KB)
    float* partial = (float*)((char*)d_ws + (2u << 20));     // [2MB, 18MB)

    w_pack_bf16<<<128, 256, 0, stream>>>(W, Bpack, flags);
    router_gemm<<<(N_TOKENS / NT_BLK) * KS, 256, 0, stream>>>(x, Bpack, partial);
    finalize   <<<N_TOKENS / 4, 256, 0, stream>>>(partial, out, flags);
    refine     <<<128, 256, 0, stream>>>(x, W, flags, out);
}

// Round 16
// 109.229 us; speedup vs baseline: 1.1447x; 1.0455x over previous
//
#include <hip/hip_runtime.h>
#include <math.h>

#define N_EMBD    4096
#define N_EXPERTS 64
#define N_TOKENS  16384
#define TAU       1e-3f
#define NT_BLK    32                  // tokens per block
#define KS        4                   // K-split across blocks
#define K_BLK     (N_EMBD / KS)       // 1024 f32 per block
#define NT2       16                  // K-tiles (BK=64) per block

typedef __attribute__((ext_vector_type(8))) short bf16x8;
typedef __attribute__((ext_vector_type(4))) float f32x4;

#define MFMA16 __builtin_amdgcn_mfma_f32_16x16x32_bf16

struct hl_pair { unsigned h, l; };

// ---------------------------------------------------------------------------
// f32 -> (bf16 hi, bf16 lo) RNE split, pair-packed into one u32 each.
// ---------------------------------------------------------------------------
__device__ __forceinline__ hl_pair split_pair(float f0, float f1) {
    unsigned u0 = __builtin_bit_cast(unsigned, f0);
    unsigned u1 = __builtin_bit_cast(unsigned, f1);
    unsigned r0 = u0 + 0x7FFFu + ((u0 >> 16) & 1u);
    unsigned r1 = u1 + 0x7FFFu + ((u1 >> 16) & 1u);
    hl_pair p;
    p.h = (r0 >> 16) | (r1 & 0xFFFF0000u);
    float h0 = __builtin_bit_cast(float, r0 & 0xFFFF0000u);
    float h1 = __builtin_bit_cast(float, r1 & 0xFFFF0000u);
    float l0 = f0 - h0;
    float l1 = f1 - h1;
    unsigned v0 = __builtin_bit_cast(unsigned, l0);
    unsigned v1 = __builtin_bit_cast(unsigned, l1);
    unsigned s0 = v0 + 0x7FFFu + ((v0 >> 16) & 1u);
    unsigned s1 = v1 + 0x7FFFu + ((v1 >> 16) & 1u);
    p.l = (s0 >> 16) | (s1 & 0xFFFF0000u);
    return p;
}

// ---------------------------------------------------------------------------
// Kernel 0: pack W into bf16 hi/lo MFMA B-fragments; zero the flag counter.
// Frag F = ks*8 + nt*2 + term. Lane l elem j = W[nt*16+(l&15)][ks*32+(l>>4)*8+j]
// ---------------------------------------------------------------------------
__global__ void w_pack_bf16(const float* __restrict__ W,
                            uint4* __restrict__ Bpack,
                            int* __restrict__ flags) {
    int tid = blockIdx.x * blockDim.x + threadIdx.x;   // 32768
    if (tid == 0) flags[0] = 0;
    int lane = tid & 63;
    int nt   = (tid >> 6) & 3;
    int ks   = tid >> 8;                               // 0..127
    int e = nt * 16 + (lane & 15);
    int k = ks * 32 + ((lane >> 4) << 3);
    const float* src = W + (size_t)e * N_EMBD + k;
    uint4 hp, lp;
    hl_pair p0 = split_pair(src[0], src[1]);
    hl_pair p1 = split_pair(src[2], src[3]);
    hl_pair p2 = split_pair(src[4], src[5]);
    hl_pair p3 = split_pair(src[6], src[7]);
    hp.x = p0.h; lp.x = p0.l;
    hp.y = p1.h; lp.y = p1.l;
    hp.z = p2.h; lp.z = p2.l;
    hp.w = p3.h; lp.w = p3.l;
    size_t F = (size_t)ks * 8 + nt * 2;
    Bpack[F * 64 + lane]       = hp;
    Bpack[(F + 1) * 64 + lane] = lp;
}

// ---------------------------------------------------------------------------
// Split 8 f32 into bf16 hi/lo uint4s and ds_write_b128 to the two planes.
// ---------------------------------------------------------------------------
__device__ __forceinline__ void store_split8(char* buf, int off, f32x4 a, f32x4 b) {
    hl_pair p0 = split_pair(a.x, a.y);
    hl_pair p1 = split_pair(a.z, a.w);
    hl_pair p2 = split_pair(b.x, b.y);
    hl_pair p3 = split_pair(b.z, b.w);
    uint4 h, l;
    h.x = p0.h; h.y = p1.h; h.z = p2.h; h.w = p3.h;
    l.x = p0.l; l.y = p1.l; l.z = p2.l; l.w = p3.l;
    *(uint4*)(buf + off)        = h;
    *(uint4*)(buf + off + 4096) = l;
}

// ---------------------------------------------------------------------------
// Kernel 1: router GEMM — BOTH operands prefetched one full tile ahead.
// r6-r15 plateau root cause: B fragments were loaded AT USE every tile; since
// vmcnt drains in order (m135), waiting for B force-drained every younger
// A-prefetch -> full latency exposed per tile, convoy-amplified by barriers.
// Here: B(t+1) -> regs and A(t+2) -> regs are ISSUED at the top of tile t's
// phase (sched_barrier(0) stops the compiler sinking them; it reads no regs
// so it inserts no wait -- unlike r15's value-pins). Uses of B(t)/A(t+1)
// then get compiler-counted vmcnt(8)/vmcnt(6), never a drain.
// Geometry = r13 (verified): block = 32 tokens x K-quarter, 4 waves, wave =
// expert-quarter x 2 M-tiles, BK=64, conflict-free swizzle both sides.
// partial layout: [KS][N_TOKENS][64] f32.
// ---------------------------------------------------------------------------
__global__ __launch_bounds__(256, 5) void router_gemm(
        const float* __restrict__ x,
        const uint4* __restrict__ Bpack,
        float* __restrict__ partial) {
    __shared__ __align__(16) char ldsA[2 * 8192];   // dbuf x {hi 4KB, lo 4KB}

    const int tid  = threadIdx.x;
    const int lane = tid & 63;
    const int w    = tid >> 6;                  // wave = expert quarter
    const int kq   = blockIdx.x & 3;            // K quarter
    const int tok0 = (blockIdx.x >> 2) * NT_BLK;
    const int l15 = lane & 15, l16 = lane >> 4;

    // staging: thread -> row tid>>3 (0..31), 8-f32 chunk c8 = tid&7
    const int row_w = tid >> 3;
    const int c8    = tid & 7;
    const f32x4* g = (const f32x4*)(x + (size_t)(tok0 + row_w) * N_EMBD
                                      + kq * K_BLK + c8 * 8);
    const int wo = row_w * 128 + ((c8 * 16) ^ ((row_w & 7) << 4));

    // fragment read offsets (conflict-free: 8 lanes/bank-quad both sides)
    const int swz_r = (l15 & 7) << 4;
    const int ro0 = l15 * 128 + ((l16 * 16)      ^ swz_r);
    const int ro1 = l15 * 128 + ((64 + l16 * 16) ^ swz_r);

    f32x4 acc0 = {0.f, 0.f, 0.f, 0.f};
    f32x4 acc1 = {0.f, 0.f, 0.f, 0.f};
    f32x4 ra0, ra1, rb0, rb1;                   // A f32 prefetch (2 tiles)
    uint4 bah0, bal0, bah1, bal1;               // B regs, buffer a
    uint4 bbh0, bbl0, bbh1, bbl1;               // B regs, buffer b

    char* buf0 = ldsA;
    char* buf1 = ldsA + 8192;

    const uint4* bbase = Bpack + ((size_t)(kq * 32) * 8 + w * 2) * 64 + lane;

#define LOADA(P, t) { P##0 = g[(t) * 16]; P##1 = g[(t) * 16 + 1]; }
#define LOADB(P, tt) { const uint4* _q = bbase + (size_t)(tt) * 1024;         \
    P##h0 = _q[0]; P##l0 = _q[64]; P##h1 = _q[512]; P##l1 = _q[576]; }
#define STOREA(buf, P) store_split8(buf, wo, P##0, P##1)
#define COMPUTE(bufR, B) {                                                    \
    bf16x8 bh0 = __builtin_bit_cast(bf16x8, B##h0);                           \
    bf16x8 bl0 = __builtin_bit_cast(bf16x8, B##l0);                           \
    bf16x8 bh1 = __builtin_bit_cast(bf16x8, B##h1);                           \
    bf16x8 bl1 = __builtin_bit_cast(bf16x8, B##l1);                           \
    bf16x8 a;                                                                 \
    a = *(const bf16x8*)((bufR) + ro0);                                       \
    acc0 = MFMA16(a, bh0, acc0, 0, 0, 0);                                     \
    acc0 = MFMA16(a, bl0, acc0, 0, 0, 0);                                     \
    a = *(const bf16x8*)((bufR) + ro0 + 4096);                                \
    acc0 = MFMA16(a, bh0, acc0, 0, 0, 0);                                     \
    a = *(const bf16x8*)((bufR) + ro0 + 2048);                                \
    acc1 = MFMA16(a, bh0, acc1, 0, 0, 0);                                     \
    acc1 = MFMA16(a, bl0, acc1, 0, 0, 0);                                     \
    a = *(const bf16x8*)((bufR) + ro0 + 2048 + 4096);                         \
    acc1 = MFMA16(a, bh0, acc1, 0, 0, 0);                                     \
    a = *(const bf16x8*)((bufR) + ro1);                                       \
    acc0 = MFMA16(a, bh1, acc0, 0, 0, 0);                                     \
    acc0 = MFMA16(a, bl1, acc0, 0, 0, 0);                                     \
    a = *(const bf16x8*)((bufR) + ro1 + 4096);                                \
    acc0 = MFMA16(a, bh1, acc0, 0, 0, 0);                                     \
    a = *(const bf16x8*)((bufR) + ro1 + 2048);                                \
    acc1 = MFMA16(a, bh1, acc1, 0, 0, 0);                                     \
    acc1 = MFMA16(a, bl1, acc1, 0, 0, 0);                                     \
    a = *(const bf16x8*)((bufR) + ro1 + 2048 + 4096);                         \
    acc1 = MFMA16(a, bh1, acc1, 0, 0, 0);                                     \
}

    // prologue: stage tile 0; issue B(0) and A(1)
    LOADA(rb, 0);
    STOREA(buf0, rb);                          // one-time stall for A(0)
    LOADB(ba, 0);
    LOADA(ra, 1);
    __builtin_amdgcn_sched_barrier(0);         // keep issues above
    asm volatile("s_waitcnt lgkmcnt(0)" ::: "memory");
    __builtin_amdgcn_s_barrier();
    __builtin_amdgcn_sched_barrier(0);

    for (int t = 0; t < NT2; t += 2) {
        // ---- phase A: compute tile t (buf0, B=ba); stage A(t+1)=ra ----
        LOADB(bb, t + 1);                      // B(t+1), used next phase
        if (t + 2 < NT2) LOADA(rb, t + 2);     // A(t+2)
        __builtin_amdgcn_sched_barrier(0);     // issues stay ABOVE compute
        COMPUTE(buf0, ba);                     // waits ba only (8 younger ok)
        STOREA(buf1, ra);                      // waits ra only (6 younger ok)
        asm volatile("s_waitcnt lgkmcnt(0)" ::: "memory");
        __builtin_amdgcn_s_barrier();
        __builtin_amdgcn_sched_barrier(0);

        // ---- phase B: compute tile t+1 (buf1, B=bb); stage A(t+2)=rb ----
        if (t + 2 < NT2) {
            LOADB(ba, t + 2);
            if (t + 3 < NT2) LOADA(ra, t + 3);
            __builtin_amdgcn_sched_barrier(0);
            COMPUTE(buf1, bb);
            STOREA(buf0, rb);
            asm volatile("s_waitcnt lgkmcnt(0)" ::: "memory");
            __builtin_amdgcn_s_barrier();
            __builtin_amdgcn_sched_barrier(0);
        } else {
            COMPUTE(buf1, bb);                 // final tile, no prefetch
        }
    }
#undef LOADA
#undef LOADB
#undef STOREA
#undef COMPUTE

    // C layout: row(token in M-tile) = l16*4 + j, col(expert in quarter) = l15
    float* po = partial + ((size_t)kq * N_TOKENS + tok0) * 64 + w * 16 + l15;
#pragma unroll
    for (int j = 0; j < 4; ++j) {
        po[(size_t)(l16 * 4 + j) * 64]      = acc0[j];
        po[(size_t)(16 + l16 * 4 + j) * 64] = acc1[j];
    }
}

// ---------------------------------------------------------------------------
// Kernel 2: finalize. Wave per token; sum 4 K-quarter partials; top-3
// butterflies; softmax of top-2; near-tie flagging for refine.
// ---------------------------------------------------------------------------
__global__ void finalize(const float* __restrict__ partial,
                         float* __restrict__ out,
                         int* __restrict__ flags) {
    const int lane = threadIdx.x & 63;
    const int tok  = blockIdx.x * 4 + (threadIdx.x >> 6);

    float v = partial[(size_t)tok * 64 + lane]
            + partial[((size_t)N_TOKENS + tok) * 64 + lane]
            + partial[((size_t)2 * N_TOKENS + tok) * 64 + lane]
            + partial[((size_t)3 * N_TOKENS + tok) * 64 + lane];

    float m1 = v; int i1 = lane;
#pragma unroll
    for (int off = 32; off; off >>= 1) {
        float ov = __shfl_xor(m1, off); int oi = __shfl_xor(i1, off);
        if (ov > m1 || (ov == m1 && oi < i1)) { m1 = ov; i1 = oi; }
    }
    float m2 = (lane == i1) ? -INFINITY : v; int i2 = lane;
#pragma unroll
    for (int off = 32; off; off >>= 1) {
        float ov = __shfl_xor(m2, off); int oi = __shfl_xor(i2, off);
        if (ov > m2 || (ov == m2 && oi < i2)) { m2 = ov; i2 = oi; }
    }
    float m3 = (lane == i1 || lane == i2) ? -INFINITY : v;
#pragma unroll
    for (int off = 32; off; off >>= 1)
        m3 = fmaxf(m3, __shfl_xor(m3, off));

    if (lane == 0) {
        float e2  = __expf(m2 - m1);
        float inv = 1.0f / (1.0f + e2);
        float2 idx = make_float2((float)i1, (float)i2);
        float2 gts = make_float2(inv, e2 * inv);
        *(float2*)(out + 2 * tok) = idx;
        *(float2*)(out + 2 * N_TOKENS + 2 * tok) = gts;
        if ((m1 - m2 < TAU) || (m2 - m3 < TAU)) {
            int p = atomicAdd(flags, 1);
            if (p < N_TOKENS) flags[1 + p] = tok;
        }
    }
}

// ---------------------------------------------------------------------------
// Kernel 3: exact f64 refinement of flagged near-tie tokens. Block per token
// (grid-strided). Wave wv handles experts wv*16..+16, lanes split K.
// ---------------------------------------------------------------------------
__global__ __launch_bounds__(256) void refine(const float* __restrict__ x,
                                              const float* __restrict__ W,
                                              const int* __restrict__ flags,
                                              float* __restrict__ out) {
    __shared__ double redd[64];
    const int lane = threadIdx.x & 63;
    const int wv   = threadIdx.x >> 6;
    int cnt = flags[0];
    if (cnt > N_TOKENS) cnt = N_TOKENS;

    for (int i = blockIdx.x; i < cnt; i += gridDim.x) {
        const int tok = flags[1 + i];
        const float4* xr4 = (const float4*)(x + (size_t)tok * N_EMBD);
#pragma unroll
        for (int ee = 0; ee < 16; ++ee) {
            const int e = wv * 16 + ee;
            const float4* wr = (const float4*)(W + (size_t)e * N_EMBD);
            double acc = 0.0;
#pragma unroll 4
            for (int c = 0; c < 16; ++c) {
                float4 xv = xr4[c * 64 + lane];
                float4 wq = wr[c * 64 + lane];
                acc += (double)xv.x * wq.x + (double)xv.y * wq.y
                     + (double)xv.z * wq.z + (double)xv.w * wq.w;
            }
#pragma unroll
            for (int off = 32; off; off >>= 1)
                acc += __shfl_xor(acc, off);
            if (lane == 0) redd[e] = acc;
        }
        __syncthreads();
        if (wv == 0) {
            double v = redd[lane];
            double m1 = v; int i1 = lane;
#pragma unroll
            for (int off = 32; off; off >>= 1) {
                double ov = __shfl_xor(m1, off); int oi = __shfl_xor(i1, off);
                if (ov > m1 || (ov == m1 && oi < i1)) { m1 = ov; i1 = oi; }
            }
            double m2 = (lane == i1) ? -INFINITY : v; int i2 = lane;
#pragma unroll
            for (int off = 32; off; off >>= 1) {
                double ov = __shfl_xor(m2, off); int oi = __shfl_xor(i2, off);
                if (ov > m2 || (ov == m2 && oi < i2)) { m2 = ov; i2 = oi; }
            }
            if (lane == 0) {
                double e2  = exp(m2 - m1);
                double inv = 1.0 / (1.0 + e2);
                out[2 * tok + 0] = (float)i1;
                out[2 * tok + 1] = (float)i2;
                out[2 * N_TOKENS + 2 * tok + 0] = (float)inv;
                out[2 * N_TOKENS + 2 * tok + 1] = (float)(e2 * inv);
            }
        }
        __syncthreads();
    }
}

// ---------------------------------------------------------------------------
extern "C" void kernel_launch(void* const* d_in, const int* in_sizes, int n_in,
                              void* d_out, int out_size, void* d_ws, size_t ws_size,
                              hipStream_t stream) {
    const float* x = (const float*)d_in[0];
    const float* W = (const float*)d_in[1];
    float* out = (float*)d_out;

    uint4* Bpack   = (uint4*)d_ws;                           // [0, 1MB)
    int*   flags   = (int*)((char*)d_ws + (1u << 20));       // [1MB, +64KB)
    float* partial = (float*)((char*)d_ws + (2u << 20));     // [2MB, 18MB)

    w_pack_bf16<<<128, 256, 0, stream>>>(W, Bpack, flags);
    router_gemm<<<(N_TOKENS / NT_BLK) * KS, 256, 0, stream>>>(x, Bpack, partial);
    finalize   <<<N_TOKENS / 4, 256, 0, stream>>>(partial, out, flags);
    refine     <<<128, 256, 0, stream>>>(x, W, flags, out);
}